// Round 12
// baseline (82.730 us; speedup 1.0000x reference)
//
#include <hip/hip_runtime.h>
#include <stdint.h>

#define NN 4096
#define NB 32          // NN / 128
#define BK 64          // K-step (2 x 16x16x32 MFMA k-slots)

// trimm grid layout: [0,272) heavy half-units (d>=16), [272,664) light tiles
// (d<=15), [664,1160) strict-upper zero tiles.
#define NHEAVY 136
#define NHUNITS 272
#define ZBASE 664
#define TGRID 1160

// prep grid: [0,4096) A rows, [4096,8192) B 64x64 subtiles,
// [8192,8328) heavy-C zero (atomic-fallback mode only)
#define PGRID_W 8192
#define PGRID_A 8328

typedef __bf16 bf16x8 __attribute__((ext_vector_type(8)));
typedef float f32x4 __attribute__((ext_vector_type(4)));
typedef unsigned short ushort8 __attribute__((ext_vector_type(8)));

// RTNE fp32 -> bf16
__device__ __forceinline__ unsigned short f2bf(float x) {
    union { float f; unsigned int u; } v; v.f = x;
    unsigned int u = v.u;
    u += 0x7fffu + ((u >> 16) & 1u);
    return (unsigned short)(u >> 16);
}

// async global->LDS, 16B per lane; LDS dest is wave-uniform base + lane*16
#define GLOAD16(g, l) __builtin_amdgcn_global_load_lds( \
    (const __attribute__((address_space(1))) unsigned int*)(g), \
    (__attribute__((address_space(3))) unsigned int*)(l), 16, 0, 0)

// heavy tile index h (0..135) -> (bi,bj), d descending from 31 to 16
__device__ __forceinline__ void heavy_map(int h, int& bi, int& bj) {
    int t = h, d = NB - 1;
    while (t >= NB - d) { t -= NB - d; --d; }
    bj = t; bi = t + d;
}

// ---- fused prep: A lower-prefix convert, B lower transpose-convert ----
__global__ __launch_bounds__(256) void prep(const float* __restrict__ A,
                                            const float* __restrict__ B,
                                            unsigned short* __restrict__ Ab,
                                            unsigned short* __restrict__ Bt,
                                            float* __restrict__ C) {
    __shared__ float tile[64][65];
    int bid = blockIdx.x;
    int tid = threadIdx.x;

    if (bid < 4096) {
        // A row i: convert fp32 prefix [0, ((i>>7)+1)*128) to bf16
        int i = bid;
        int nslots = (((i >> 7) + 1) * 128) >> 3;   // 8 floats per slot
        const float4* src = reinterpret_cast<const float4*>(A + (size_t)i * NN);
        unsigned short* dst = Ab + (size_t)i * NN;
        for (int p = tid; p < nslots; p += 256) {
            float4 x0 = src[p * 2], x1 = src[p * 2 + 1];
            ushort8 o;
            o[0] = f2bf(x0.x); o[1] = f2bf(x0.y); o[2] = f2bf(x0.z); o[3] = f2bf(x0.w);
            o[4] = f2bf(x1.x); o[5] = f2bf(x1.y); o[6] = f2bf(x1.z); o[7] = f2bf(x1.w);
            *reinterpret_cast<ushort8*>(dst + p * 8) = o;
        }
        return;
    }
    if (bid < 8192) {
        // B 64x64 subtile transpose: needed iff k64 >= (n64 & ~1)  (128-tile lower superset)
        int s = bid - 4096;
        int n64 = s >> 6, k64 = s & 63;
        if (k64 < (n64 & ~1)) return;
        int n0 = n64 * 64, k0 = k64 * 64;
        int tx = tid & 63, ty = tid >> 6;
#pragma unroll
        for (int r = 0; r < 16; ++r) {
            int k = ty + r * 4;
            tile[k][tx] = B[(size_t)(k0 + k) * NN + n0 + tx];
        }
        __syncthreads();
#pragma unroll
        for (int r = 0; r < 16; ++r) {
            int n = ty + r * 4;
            Bt[(size_t)(n0 + n) * NN + k0 + tx] = f2bf(tile[tx][n]);
        }
        return;
    }
    // zero-init heavy C tile (atomic-fallback mode only)
    int h = bid - 8192;
    int bi, bj; heavy_map(h, bi, bj);
    float4 z = make_float4(0.f, 0.f, 0.f, 0.f);
    float4* cp = reinterpret_cast<float4*>(C + (size_t)bi * 128 * NN + (size_t)bj * 128);
#pragma unroll
    for (int i2 = 0; i2 < 16; ++i2) {
        int slot = tid + i2 * 256;
        int row = slot >> 5, c4 = slot & 31;
        cp[(size_t)row * (NN / 4) + c4] = z;
    }
}

// ---- triangular GEMM: 128^2 tile, BK=64, 2 blocks/CU, counted-vmcnt 2-deep ----
__global__ __launch_bounds__(256, 2) void trimm(const unsigned short* __restrict__ Ab,
                                                const unsigned short* __restrict__ Bt,
                                                float* __restrict__ C,
                                                float* __restrict__ W,
                                                int useW) {
    int bid = blockIdx.x;
    int tid = threadIdx.x;
    int lane = tid & 63;
    int w = tid >> 6;

    if (bid >= ZBASE) {
        // strict upper tile: zero-fill 128x128
        int t = bid - ZBASE;
        int r = 0, cnt = NB - 1;
        while (t >= cnt) { t -= cnt; ++r; --cnt; }
        int bi = r, bj = r + 1 + t;
        float4 z = make_float4(0.f, 0.f, 0.f, 0.f);
        float4* cp = reinterpret_cast<float4*>(C + (size_t)bi * 128 * NN + (size_t)bj * 128);
#pragma unroll
        for (int i2 = 0; i2 < 16; ++i2) {
            int slot = tid + i2 * 256;
            int row = slot >> 5, c4 = slot & 31;
            cp[(size_t)row * (NN / 4) + c4] = z;
        }
        return;
    }

    int bi, bj;
    bool heavy = false;
    int h = 0, half = 0;
    int k_lo, k_hi;

    if (bid < NHUNITS) {
        // heavy half-unit: tile h = bid>>1, K-half = bid&1
        heavy = true;
        h = bid >> 1; half = bid & 1;
        heavy_map(h, bi, bj);
        k_lo = bj * 128;
        k_hi = (bi + 1) * 128;
        int len = (k_hi - k_lo) >> 1;      // (d+1)*64 -> multiple of BK
        if (half == 0) k_hi = k_lo + len;
        else           k_lo = k_lo + len;
    } else {
        // light tile, d = 15..0 descending
        int t = bid - NHUNITS, d = 15;
        while (t >= NB - d) { t -= NB - d; --d; }
        bj = t; bi = t + d;
        k_lo = bj * 128;
        k_hi = (bi + 1) * 128;
    }

    __shared__ unsigned short As[2][128 * BK];   // 2 x 16 KB
    __shared__ unsigned short Bs[2][128 * BK];   // 2 x 16 KB  (64 KB total -> 2 blocks/CU)

    int wr = w >> 1, wc = w & 1;

    // staging: LDS linear [row][8 x 16B-chunk]; source pre-swizzled so stored
    // chunk c of row r holds global chunk c^(r&7). Thread t covers rows
    // g*32 + (t>>3), chunk t&7, g=0..3 (per matrix).
    int srow = tid >> 3;
    int schunk = ((tid & 7) ^ (srow & 7)) * 8;
    const unsigned short* gA = Ab + (size_t)(bi * 128 + srow) * NN + schunk;
    const unsigned short* gB = Bt + (size_t)(bj * 128 + srow) * NN + schunk;

    f32x4 acc[4][4];
#pragma unroll
    for (int mi = 0; mi < 4; ++mi)
#pragma unroll
        for (int ni = 0; ni < 4; ++ni)
            acc[mi][ni] = (f32x4){0.f, 0.f, 0.f, 0.f};

    // fragment reads: row = (wr|wc)*64 + m*16 + (lane&15); want global chunk
    // (lane>>4) [kslot0] / 4|(lane>>4) [kslot1]; stored at chunk^(row&7),
    // row&7 == lane&7.
    int fr = lane & 15;
    int c0 = (((lane >> 4) ^ (lane & 7)) * 8);
    int c1 = ((((lane >> 4) | 4) ^ (lane & 7)) * 8);
    int arow = wr * 64 + fr;
    int brow = wc * 64 + fr;

#define STAGE(bufsel, kk) do { \
        unsigned short* la_ = &As[bufsel][0] + tid * 8; \
        unsigned short* lb_ = &Bs[bufsel][0] + tid * 8; \
        GLOAD16(gA + (kk), la_); \
        GLOAD16(gA + (kk) + (size_t)32 * NN, la_ + 2048); \
        GLOAD16(gA + (kk) + (size_t)64 * NN, la_ + 4096); \
        GLOAD16(gA + (kk) + (size_t)96 * NN, la_ + 6144); \
        GLOAD16(gB + (kk), lb_); \
        GLOAD16(gB + (kk) + (size_t)32 * NN, lb_ + 2048); \
        GLOAD16(gB + (kk) + (size_t)64 * NN, lb_ + 4096); \
        GLOAD16(gB + (kk) + (size_t)96 * NN, lb_ + 6144); \
    } while (0)

    int nt = (k_hi - k_lo) >> 6;   // >= 2 always

    // prologue: 2-deep (16 loads in flight)
    STAGE(0, k_lo);
    STAGE(1, k_lo + BK);
    int cur = 0;

    for (int t = 0; t < nt; ++t) {
        // own 8 oldest loads (buf[cur]) landed; 8 newer may stay in flight
        asm volatile("s_waitcnt vmcnt(8)" ::: "memory");
        __builtin_amdgcn_s_barrier();   // all waves' buf[cur] loads visible

        const unsigned short* Ac = &As[cur][0];
        const unsigned short* Bc = &Bs[cur][0];
        bf16x8 a0[4], a1[4], b0[4], b1[4];
#pragma unroll
        for (int m = 0; m < 4; ++m) {
            a0[m] = *reinterpret_cast<const bf16x8*>(&Ac[(arow + m * 16) * BK + c0]);
            a1[m] = *reinterpret_cast<const bf16x8*>(&Ac[(arow + m * 16) * BK + c1]);
        }
#pragma unroll
        for (int n = 0; n < 4; ++n) {
            b0[n] = *reinterpret_cast<const bf16x8*>(&Bc[(brow + n * 16) * BK + c0]);
            b1[n] = *reinterpret_cast<const bf16x8*>(&Bc[(brow + n * 16) * BK + c1]);
        }
        __builtin_amdgcn_s_setprio(1);
#pragma unroll
        for (int m = 0; m < 4; ++m)
#pragma unroll
            for (int n = 0; n < 4; ++n) {
                acc[m][n] = __builtin_amdgcn_mfma_f32_16x16x32_bf16(a0[m], b0[n], acc[m][n], 0, 0, 0);
                acc[m][n] = __builtin_amdgcn_mfma_f32_16x16x32_bf16(a1[m], b1[n], acc[m][n], 0, 0, 0);
            }
        __builtin_amdgcn_s_setprio(0);

        __builtin_amdgcn_s_barrier();   // all waves done reading buf[cur]

        // stage tile t+2 into buf[cur]; uniform dummy re-stage at tail keeps
        // per-wave vmcnt arithmetic constant (8 issued every iteration)
        int kn = k_lo + (t + 2) * BK;
        if (kn >= k_hi) kn = k_lo;
        STAGE(cur, kn);

        cur ^= 1;
    }
    asm volatile("s_waitcnt vmcnt(0)" ::: "memory");  // drain dummies before LDS dealloc
#undef STAGE

    // epilogue: C/D layout col = lane&15, row = (lane>>4)*4 + reg
    int trow0 = wr * 64 + (lane >> 4) * 4;    // row within tile
    int tcol0 = wc * 64 + fr;                 // col within tile
    int crow0 = bi * 128 + trow0;
    int ccol0 = bj * 128 + tcol0;
    if (heavy && useW) {
        if (half == 1) {
            // store partial to workspace tile W[h] (128x128 row-major)
            float* wb = W + (size_t)h * 16384;
#pragma unroll
            for (int mi = 0; mi < 4; ++mi)
#pragma unroll
                for (int ni = 0; ni < 4; ++ni) {
                    float* wp = wb + (size_t)(trow0 + mi * 16) * 128 + tcol0 + ni * 16;
#pragma unroll
                    for (int r2 = 0; r2 < 4; ++r2)
                        wp[r2 * 128] = acc[mi][ni][r2];
                }
        } else {
            // half 0: plain store to C (merge kernel adds W later)
#pragma unroll
            for (int mi = 0; mi < 4; ++mi)
#pragma unroll
                for (int ni = 0; ni < 4; ++ni) {
                    float* cp = C + (size_t)(crow0 + mi * 16) * NN + ccol0 + ni * 16;
#pragma unroll
                    for (int r2 = 0; r2 < 4; ++r2)
                        cp[(size_t)r2 * NN] = acc[mi][ni][r2];
                }
        }
    } else if (heavy) {
        // atomic fallback (C pre-zeroed by prep)
#pragma unroll
        for (int mi = 0; mi < 4; ++mi)
#pragma unroll
            for (int ni = 0; ni < 4; ++ni) {
                float* cp = C + (size_t)(crow0 + mi * 16) * NN + ccol0 + ni * 16;
#pragma unroll
                for (int r2 = 0; r2 < 4; ++r2)
                    atomicAdd(&cp[(size_t)r2 * NN], acc[mi][ni][r2]);
            }
    } else {
#pragma unroll
        for (int mi = 0; mi < 4; ++mi)
#pragma unroll
            for (int ni = 0; ni < 4; ++ni) {
                float* cp = C + (size_t)(crow0 + mi * 16) * NN + ccol0 + ni * 16;
#pragma unroll
                for (int r2 = 0; r2 < 4; ++r2)
                    cp[(size_t)r2 * NN] = acc[mi][ni][r2];
            }
    }
}

// ---- merge: C[heavy tile h] += W[h] ----
__global__ __launch_bounds__(256) void merge(const float* __restrict__ W,
                                             float* __restrict__ C) {
    int h = blockIdx.x;
    int tid = threadIdx.x;
    int bi, bj; heavy_map(h, bi, bj);
    const float4* wv = reinterpret_cast<const float4*>(W + (size_t)h * 16384);
    float4* cp = reinterpret_cast<float4*>(C + (size_t)bi * 128 * NN + (size_t)bj * 128);
#pragma unroll
    for (int i2 = 0; i2 < 16; ++i2) {
        int slot = tid + i2 * 256;          // 0..4095: row = slot>>5, col4 = slot&31
        int row = slot >> 5, c4 = slot & 31;
        float4 a = cp[(size_t)row * (NN / 4) + c4];
        float4 b = wv[slot];
        a.x += b.x; a.y += b.y; a.z += b.z; a.w += b.w;
        cp[(size_t)row * (NN / 4) + c4] = a;
    }
}

extern "C" void kernel_launch(void* const* d_in, const int* in_sizes, int n_in,
                              void* d_out, int out_size, void* d_ws, size_t ws_size,
                              hipStream_t stream) {
    const float* A = (const float*)d_in[0];
    const float* B = (const float*)d_in[1];
    float* C = (float*)d_out;
    unsigned short* Ab = (unsigned short*)d_ws;            // 32 MB bf16 A (lower tiles valid)
    unsigned short* Bt = Ab + (size_t)NN * NN;             // 32 MB bf16 B^T (needed tiles valid)
    const size_t base = (size_t)2 * NN * NN * sizeof(unsigned short);   // 64 MB
    const size_t wbytes = (size_t)NHEAVY * 16384 * sizeof(float);       // 8.9 MB
    const int useW = (ws_size >= base + wbytes) ? 1 : 0;
    float* W = (float*)((char*)d_ws + base);

    prep<<<useW ? PGRID_W : PGRID_A, 256, 0, stream>>>(A, B, Ab, Bt, C);
    trimm<<<TGRID, 256, 0, stream>>>(Ab, Bt, C, W, useW);
    if (useW) merge<<<NHEAVY, 256, 0, stream>>>(W, C);
}

// Round 13
// 75.211 us; speedup vs baseline: 1.1000x; 1.1000x over previous
//
#include <hip/hip_runtime.h>
#include <stdint.h>

#define NN 4096
#define NB 32          // NN / 128
#define BK 64          // K-step (2 x 16x16x32 MFMA k-slots)

// trimm grid: [0,664) compute units, XCD-affine: unit at bid has
// XCD x = bid%8 owning tile-rows {31-x, 16+x, 15-x, x} (83 units per XCD:
// heavies of rows 31-x & 16+x split 2-way in K, then lights).
// [664,1160) strict-upper zero tiles.
#define NCOMP 664
#define ZBASE 664
#define TGRID 1160

// prep grid: [0,4096) A rows, [4096,8192) B 64x64 subtiles, [8192,8328) heavy-C zero
#define PGRID 8328

typedef __bf16 bf16x8 __attribute__((ext_vector_type(8)));
typedef float f32x4 __attribute__((ext_vector_type(4)));
typedef unsigned short ushort8 __attribute__((ext_vector_type(8)));

// RTNE fp32 -> bf16
__device__ __forceinline__ unsigned short f2bf(float x) {
    union { float f; unsigned int u; } v; v.f = x;
    unsigned int u = v.u;
    u += 0x7fffu + ((u >> 16) & 1u);
    return (unsigned short)(u >> 16);
}

// async global->LDS, 16B per lane; LDS dest is wave-uniform base + lane*16
#define GLOAD16(g, l) __builtin_amdgcn_global_load_lds( \
    (const __attribute__((address_space(1))) unsigned int*)(g), \
    (__attribute__((address_space(3))) unsigned int*)(l), 16, 0, 0)

// heavy tile index h (0..135) -> (bi,bj), d descending from 31 to 16 (prep zero-init)
__device__ __forceinline__ void heavy_map(int h, int& bi, int& bj) {
    int t = h, d = NB - 1;
    while (t >= NB - d) { t -= NB - d; --d; }
    bj = t; bi = t + d;
}

// ---- fused prep: A lower-prefix convert, B lower transpose-convert, heavy-C zero ----
__global__ __launch_bounds__(256) void prep(const float* __restrict__ A,
                                            const float* __restrict__ B,
                                            unsigned short* __restrict__ Ab,
                                            unsigned short* __restrict__ Bt,
                                            float* __restrict__ C) {
    __shared__ float tile[64][65];
    int bid = blockIdx.x;
    int tid = threadIdx.x;

    if (bid < 4096) {
        // A row i: convert fp32 prefix [0, ((i>>7)+1)*128) to bf16
        int i = bid;
        int nslots = (((i >> 7) + 1) * 128) >> 3;   // 8 floats per slot
        const float4* src = reinterpret_cast<const float4*>(A + (size_t)i * NN);
        unsigned short* dst = Ab + (size_t)i * NN;
        for (int p = tid; p < nslots; p += 256) {
            float4 x0 = src[p * 2], x1 = src[p * 2 + 1];
            ushort8 o;
            o[0] = f2bf(x0.x); o[1] = f2bf(x0.y); o[2] = f2bf(x0.z); o[3] = f2bf(x0.w);
            o[4] = f2bf(x1.x); o[5] = f2bf(x1.y); o[6] = f2bf(x1.z); o[7] = f2bf(x1.w);
            *reinterpret_cast<ushort8*>(dst + p * 8) = o;
        }
        return;
    }
    if (bid < 8192) {
        // B 64x64 subtile transpose: needed iff k64 >= (n64 & ~1)  (128-tile lower superset)
        int s = bid - 4096;
        int n64 = s >> 6, k64 = s & 63;
        if (k64 < (n64 & ~1)) return;
        int n0 = n64 * 64, k0 = k64 * 64;
        int tx = tid & 63, ty = tid >> 6;
#pragma unroll
        for (int r = 0; r < 16; ++r) {
            int k = ty + r * 4;
            tile[k][tx] = B[(size_t)(k0 + k) * NN + n0 + tx];
        }
        __syncthreads();
#pragma unroll
        for (int r = 0; r < 16; ++r) {
            int n = ty + r * 4;
            Bt[(size_t)(n0 + n) * NN + k0 + tx] = f2bf(tile[tx][n]);
        }
        return;
    }
    // zero-init heavy C tile (atomicAdd targets; re-zeroed every call)
    int h = bid - 8192;
    int bi, bj; heavy_map(h, bi, bj);
    float4 z = make_float4(0.f, 0.f, 0.f, 0.f);
    float4* cp = reinterpret_cast<float4*>(C + (size_t)bi * 128 * NN + (size_t)bj * 128);
#pragma unroll
    for (int i2 = 0; i2 < 16; ++i2) {
        int slot = tid + i2 * 256;
        int row = slot >> 5, c4 = slot & 31;
        cp[(size_t)row * (NN / 4) + c4] = z;
    }
}

// ---- triangular GEMM: 128^2 tile, BK=64, 2 blocks/CU, counted-vmcnt 2-deep,
//      XCD row-affinity unit placement ----
__global__ __launch_bounds__(256, 2) void trimm(const unsigned short* __restrict__ Ab,
                                                const unsigned short* __restrict__ Bt,
                                                float* __restrict__ C) {
    int bid = blockIdx.x;
    int tid = threadIdx.x;
    int lane = tid & 63;
    int w = tid >> 6;

    if (bid >= ZBASE) {
        // strict upper tile: zero-fill 128x128
        int t = bid - ZBASE;
        int r = 0, cnt = NB - 1;
        while (t >= cnt) { t -= cnt; ++r; --cnt; }
        int bi = r, bj = r + 1 + t;
        float4 z = make_float4(0.f, 0.f, 0.f, 0.f);
        float4* cp = reinterpret_cast<float4*>(C + (size_t)bi * 128 * NN + (size_t)bj * 128);
#pragma unroll
        for (int i2 = 0; i2 < 16; ++i2) {
            int slot = tid + i2 * 256;
            int row = slot >> 5, c4 = slot & 31;
            cp[(size_t)row * (NN / 4) + c4] = z;
        }
        return;
    }

    // XCD-affine unit decode: x = bid%8 (round-robin XCD heuristic), s = bid/8.
    // XCD x owns rows rA=31-x (heavy 2*(16-x), light 16), rB=16+x (heavy
    // 2*(x+1), light 16), rC=15-x (light 16-x), rD=x (light x+1). Total 83.
    int bi, bj;
    bool heavy = false;
    int k_lo, k_hi;
    {
        int x = bid & 7, s = bid >> 3;
        int rA = 31 - x, rB = 16 + x, rC = 15 - x, rD = x;
        int nHA = 2 * (16 - x);
        int nHB = 2 * (x + 1);
        int d;
        if (s < nHA) {                    // rA heavy half-units, d desc rA..16
            heavy = true;
            int p = s >> 1, half = s & 1;
            bi = rA; d = rA - p; bj = p;
            int base = bj * 128, len = (d + 1) * 64;
            k_lo = base + (half ? len : 0);
            k_hi = k_lo + len;
        } else if (s < nHA + nHB) {       // rB heavy half-units, d desc rB..16
            heavy = true;
            int i = s - nHA;
            int p = i >> 1, half = i & 1;
            bi = rB; d = rB - p; bj = p;
            int base = bj * 128, len = (d + 1) * 64;
            k_lo = base + (half ? len : 0);
            k_hi = k_lo + len;
        } else {
            int i = s - nHA - nHB;
            if (i < 16)            { bi = rA; d = 15 - i; }
            else if (i < 32)       { bi = rB; d = 15 - (i - 16); }
            else if (i < 48 - x)   { bi = rC; d = rC - (i - 32); }
            else                   { bi = rD; d = rD - (i - (48 - x)); }
            bj = bi - d;
            k_lo = bj * 128;
            k_hi = (bi + 1) * 128;
        }
    }

    __shared__ unsigned short As[2][128 * BK];   // 2 x 16 KB
    __shared__ unsigned short Bs[2][128 * BK];   // 2 x 16 KB  (64 KB total -> 2 blocks/CU)

    int wr = w >> 1, wc = w & 1;

    // staging: LDS linear [row][8 x 16B-chunk]; source pre-swizzled so stored
    // chunk c of row r holds global chunk c^(r&7). Thread t covers rows
    // g*32 + (t>>3), chunk t&7, g=0..3 (per matrix).
    int srow = tid >> 3;
    int schunk = ((tid & 7) ^ (srow & 7)) * 8;
    const unsigned short* gA = Ab + (size_t)(bi * 128 + srow) * NN + schunk;
    const unsigned short* gB = Bt + (size_t)(bj * 128 + srow) * NN + schunk;

    f32x4 acc[4][4];
#pragma unroll
    for (int mi = 0; mi < 4; ++mi)
#pragma unroll
        for (int ni = 0; ni < 4; ++ni)
            acc[mi][ni] = (f32x4){0.f, 0.f, 0.f, 0.f};

    // fragment reads: row = (wr|wc)*64 + m*16 + (lane&15); want global chunk
    // (lane>>4) [kslot0] / 4|(lane>>4) [kslot1]; stored at chunk^(row&7),
    // row&7 == lane&7.
    int fr = lane & 15;
    int c0 = (((lane >> 4) ^ (lane & 7)) * 8);
    int c1 = ((((lane >> 4) | 4) ^ (lane & 7)) * 8);
    int arow = wr * 64 + fr;
    int brow = wc * 64 + fr;

#define STAGE(bufsel, kk) do { \
        unsigned short* la_ = &As[bufsel][0] + tid * 8; \
        unsigned short* lb_ = &Bs[bufsel][0] + tid * 8; \
        GLOAD16(gA + (kk), la_); \
        GLOAD16(gA + (kk) + (size_t)32 * NN, la_ + 2048); \
        GLOAD16(gA + (kk) + (size_t)64 * NN, la_ + 4096); \
        GLOAD16(gA + (kk) + (size_t)96 * NN, la_ + 6144); \
        GLOAD16(gB + (kk), lb_); \
        GLOAD16(gB + (kk) + (size_t)32 * NN, lb_ + 2048); \
        GLOAD16(gB + (kk) + (size_t)64 * NN, lb_ + 4096); \
        GLOAD16(gB + (kk) + (size_t)96 * NN, lb_ + 6144); \
    } while (0)

    int nt = (k_hi - k_lo) >> 6;   // >= 2 always

    // prologue: 2-deep (16 loads in flight)
    STAGE(0, k_lo);
    STAGE(1, k_lo + BK);
    int cur = 0;

    for (int t = 0; t < nt; ++t) {
        // own 8 oldest loads (buf[cur]) landed; 8 newer may stay in flight
        asm volatile("s_waitcnt vmcnt(8)" ::: "memory");
        __builtin_amdgcn_s_barrier();   // all waves' buf[cur] loads visible

        const unsigned short* Ac = &As[cur][0];
        const unsigned short* Bc = &Bs[cur][0];
        bf16x8 a0[4], a1[4], b0[4], b1[4];
#pragma unroll
        for (int m = 0; m < 4; ++m) {
            a0[m] = *reinterpret_cast<const bf16x8*>(&Ac[(arow + m * 16) * BK + c0]);
            a1[m] = *reinterpret_cast<const bf16x8*>(&Ac[(arow + m * 16) * BK + c1]);
        }
#pragma unroll
        for (int n = 0; n < 4; ++n) {
            b0[n] = *reinterpret_cast<const bf16x8*>(&Bc[(brow + n * 16) * BK + c0]);
            b1[n] = *reinterpret_cast<const bf16x8*>(&Bc[(brow + n * 16) * BK + c1]);
        }
        __builtin_amdgcn_s_setprio(1);
#pragma unroll
        for (int m = 0; m < 4; ++m)
#pragma unroll
            for (int n = 0; n < 4; ++n) {
                acc[m][n] = __builtin_amdgcn_mfma_f32_16x16x32_bf16(a0[m], b0[n], acc[m][n], 0, 0, 0);
                acc[m][n] = __builtin_amdgcn_mfma_f32_16x16x32_bf16(a1[m], b1[n], acc[m][n], 0, 0, 0);
            }
        __builtin_amdgcn_s_setprio(0);

        __builtin_amdgcn_s_barrier();   // all waves done reading buf[cur]

        // stage tile t+2 into buf[cur]; uniform dummy re-stage at tail keeps
        // per-wave vmcnt arithmetic constant (8 issued every iteration)
        int kn = k_lo + (t + 2) * BK;
        if (kn >= k_hi) kn = k_lo;
        STAGE(cur, kn);

        cur ^= 1;
    }
    asm volatile("s_waitcnt vmcnt(0)" ::: "memory");  // drain dummies before LDS dealloc
#undef STAGE

    // epilogue: C/D layout col = lane&15, row = (lane>>4)*4 + reg
    int crow0 = bi * 128 + wr * 64 + (lane >> 4) * 4;
    int ccol0 = bj * 128 + wc * 64 + fr;
    if (heavy) {
#pragma unroll
        for (int mi = 0; mi < 4; ++mi)
#pragma unroll
            for (int ni = 0; ni < 4; ++ni) {
                float* cp = C + (size_t)(crow0 + mi * 16) * NN + ccol0 + ni * 16;
#pragma unroll
                for (int r2 = 0; r2 < 4; ++r2)
                    atomicAdd(&cp[(size_t)r2 * NN], acc[mi][ni][r2]);
            }
    } else {
#pragma unroll
        for (int mi = 0; mi < 4; ++mi)
#pragma unroll
            for (int ni = 0; ni < 4; ++ni) {
                float* cp = C + (size_t)(crow0 + mi * 16) * NN + ccol0 + ni * 16;
#pragma unroll
                for (int r2 = 0; r2 < 4; ++r2)
                    cp[(size_t)r2 * NN] = acc[mi][ni][r2];
            }
    }
}

extern "C" void kernel_launch(void* const* d_in, const int* in_sizes, int n_in,
                              void* d_out, int out_size, void* d_ws, size_t ws_size,
                              hipStream_t stream) {
    const float* A = (const float*)d_in[0];
    const float* B = (const float*)d_in[1];
    float* C = (float*)d_out;
    unsigned short* Ab = (unsigned short*)d_ws;            // 32 MB bf16 A (lower tiles valid)
    unsigned short* Bt = Ab + (size_t)NN * NN;             // 32 MB bf16 B^T (needed tiles valid)
    prep<<<PGRID, 256, 0, stream>>>(A, B, Ab, Bt, C);
    trimm<<<TGRID, 256, 0, stream>>>(Ab, Bt, C);
}